// Round 5
// baseline (717.314 us; speedup 1.0000x reference)
//
#include <hip/hip_runtime.h>
#include <hip/hip_bf16.h>
#include <math.h>

#define B_   16
#define CIN_ 256
#define H_   48
#define W_   48
#define N_   2304
#define K_   64
#define CD_  64

#define GAMMA_F 0.9999999999f

using f32x4  = __attribute__((ext_vector_type(4))) float;
using bf16x8 = __attribute__((ext_vector_type(8))) short;
using s16x4  = __attribute__((ext_vector_type(4))) short;

// fp32 -> (hi, lo) bf16 pair, RNE both times.
__device__ __forceinline__ void split_bf(float x, short& hi, short& lo) {
  unsigned u = __builtin_bit_cast(unsigned, x);
  unsigned r = (u + 0x7FFFu + ((u >> 16) & 1u)) & 0xFFFF0000u;
  hi = (short)(r >> 16);
  float res = x - __builtin_bit_cast(float, r);
  unsigned u2 = __builtin_bit_cast(unsigned, res);
  unsigned r2 = u2 + 0x7FFFu + ((u2 >> 16) & 1u);
  lo = (short)(r2 >> 16);
}

// ---------------- workspace layout (floats) ----------------
constexpr size_t OFF_XF    = 0;                                  // B*N*CD (xf; later YdH/YdL bf16 planes)
constexpr size_t OFF_ANT   = OFF_XF    + (size_t)B_*N_*CD_;      // B*K*N: AcH/AcL bf16 planes (centered A)
constexpr size_t OFF_T     = OFF_ANT   + (size_t)B_*K_*N_;       // K*CD
constexpr size_t OFF_T2    = OFF_T     + (size_t)K_*CD_;         // K
constexpr size_t OFF_LOGPI = OFF_T2    + K_;                     // K
constexpr size_t OFF_I2C   = OFF_LOGPI + K_;                     // K
constexpr size_t OFF_X2    = OFF_I2C   + K_;                     // B*N (x2)
constexpr size_t OFF_CS    = OFF_X2    + (size_t)B_*N_;          // B*K
constexpr size_t OFF_ICN   = OFF_CS    + (size_t)B_*K_;          // B*K
// precomputed column-normalized spatial mask, bf16 hi/lo planes, [mcol][token]
constexpr size_t OFF_MASKH = OFF_ICN   + (size_t)B_*K_;          // N*N shorts = N*N/2 floats
constexpr size_t OFF_MASKL = OFF_MASKH + (size_t)N_*N_/2;        // N*N shorts

// ---------------- output layout (fp32 elements) ----------------
constexpr size_t OUT_OUTP = 0;
constexpr size_t OUT_ATTN = (size_t)B_*K_*N_;
constexpr size_t OUT_TNEW = OUT_ATTN + (size_t)B_*K_*N_;
constexpr size_t OUT_PI   = OUT_TNEW + (size_t)B_*K_*CD_;
constexpr size_t OUT_COV  = OUT_PI   + (size_t)B_*K_;

// ============ 1) projection: xf[b,n,c] = sum_i x[b,i,n]*w[c,i] ============
__global__ __launch_bounds__(256) void k_proj(const float* __restrict__ x, const float* __restrict__ wp,
                                              float* __restrict__ xf) {
  __shared__ float xs[32][64];
  __shared__ float ws_[32][65];
  int b = blockIdx.y, n0 = blockIdx.x * 64;
  int tid = threadIdx.x;
  int nn = tid & 63, cg = tid >> 6;
  float acc[16];
#pragma unroll
  for (int j = 0; j < 16; j++) acc[j] = 0.f;
  for (int i0 = 0; i0 < CIN_; i0 += 32) {
#pragma unroll
    for (int j = 0; j < 8; j++) {
      int ii = cg * 8 + j;
      xs[ii][nn] = x[((size_t)b * CIN_ + i0 + ii) * N_ + n0 + nn];
    }
    {
      int c = tid >> 2, iq = (tid & 3) * 8;
#pragma unroll
      for (int j = 0; j < 8; j++)
        ws_[iq + j][c] = wp[(size_t)c * CIN_ + i0 + iq + j];
    }
    __syncthreads();
#pragma unroll
    for (int ii = 0; ii < 32; ++ii) {
      float xv = xs[ii][nn];
#pragma unroll
      for (int j = 0; j < 16; j++) acc[j] += xv * ws_[ii][cg * 16 + j];
    }
    __syncthreads();
  }
  float* dst = xf + ((size_t)b * N_ + n0 + nn) * CD_ + cg * 16;
#pragma unroll
  for (int j4 = 0; j4 < 4; j4++)
    *(float4*)(dst + j4 * 4) = make_float4(acc[j4*4], acc[j4*4+1], acc[j4*4+2], acc[j4*4+3]);
}

// ============ 2) templates LN + per-k constants ============
__global__ void k_templ(const float* __restrict__ clusters, const float* __restrict__ pi,
                        const float* __restrict__ cov, const float* __restrict__ nsc,
                        const float* __restrict__ nbi, float* __restrict__ t, float* __restrict__ t2,
                        float* __restrict__ logpi, float* __restrict__ i2c) {
  int k = threadIdx.x;  // 64 threads
  float v[CD_];
  float m = 0;
#pragma unroll
  for (int c = 0; c < CD_; c++) { v[c] = clusters[k * CD_ + c]; m += v[c]; }
  m /= CD_;
  float var = 0;
#pragma unroll
  for (int c = 0; c < CD_; c++) { float d = v[c] - m; var += d * d; }
  var /= CD_;
  float inv = 1.f / sqrtf(var + 1e-5f);
  float s2 = 0;
#pragma unroll
  for (int c = 0; c < CD_; c++) {
    float tv = (v[c] - m) * inv * nsc[c] + nbi[c];
    t[k * CD_ + c] = tv;
    s2 += tv * tv;
  }
  t2[k] = s2;
  float p = pi[k], cv = cov[k];
  logpi[k] = logf(p) - 0.5f * logf(cv);
  i2c[k] = 0.5f / cv;
}

// ==== 3) distances + softmax (split-K: 4 threads/token, 16 k each) ====
__global__ __launch_bounds__(256) void k_attn(const float* __restrict__ xf, const float* __restrict__ t,
                                              const float* __restrict__ t2, const float* __restrict__ logpi,
                                              const float* __restrict__ i2c,
                                              float* __restrict__ aout, float* __restrict__ x2o) {
  __shared__ __align__(16) float ts[K_][72];
  __shared__ float t2s[K_], lps[K_], ics[K_];
  int tid = threadIdx.x;
  for (int i = tid; i < K_ * CD_; i += 256) ts[i >> 6][i & 63] = t[i];
  if (tid < K_) { t2s[tid] = t2[tid]; lps[tid] = logpi[tid]; ics[tid] = i2c[tid]; }
  __syncthreads();
  int b = blockIdx.y;
  int tok = tid >> 2, kg = tid & 3;            // 4 threads per token
  int n = blockIdx.x * 64 + tok;
  const float4* xr = (const float4*)(xf + ((size_t)b * N_ + n) * CD_);
  float4 xv[16];
#pragma unroll
  for (int i = 0; i < 16; i++) xv[i] = xr[i];
  float x2 = 0;
#pragma unroll
  for (int i = 0; i < 16; i++) x2 += xv[i].x * xv[i].x + xv[i].y * xv[i].y + xv[i].z * xv[i].z + xv[i].w * xv[i].w;
  if (kg == 0) x2o[(size_t)b * N_ + n] = x2;
  float lg[16];
#pragma unroll
  for (int kk = 0; kk < 16; kk++) {
    int k = kk * 4 + kg;
    const float4* tk = (const float4*)&ts[k][0];
    // 4 independent partial chains (fp32 reassociation only)
    float d0 = 0, d1 = 0, d2 = 0, d3 = 0;
#pragma unroll
    for (int i = 0; i < 16; i += 4) {
      float4 t0 = tk[i], t1 = tk[i + 1], t2v = tk[i + 2], t3 = tk[i + 3];
      d0 += xv[i].x * t0.x + xv[i].y * t0.y + xv[i].z * t0.z + xv[i].w * t0.w;
      d1 += xv[i+1].x * t1.x + xv[i+1].y * t1.y + xv[i+1].z * t1.z + xv[i+1].w * t1.w;
      d2 += xv[i+2].x * t2v.x + xv[i+2].y * t2v.y + xv[i+2].z * t2v.z + xv[i+2].w * t2v.w;
      d3 += xv[i+3].x * t3.x + xv[i+3].y * t3.y + xv[i+3].z * t3.z + xv[i+3].w * t3.w;
    }
    float dot = (d0 + d1) + (d2 + d3);
    lg[kk] = lps[k] - (x2 + t2s[k] - 2.f * dot) * ics[k];
  }
  float mx = lg[0];
#pragma unroll
  for (int kk = 1; kk < 16; kk++) mx = fmaxf(mx, lg[kk]);
  mx = fmaxf(mx, __shfl_xor(mx, 1));
  mx = fmaxf(mx, __shfl_xor(mx, 2));
  float sum = 0;
#pragma unroll
  for (int kk = 0; kk < 16; kk++) { lg[kk] = __expf(lg[kk] - mx); sum += lg[kk]; }
  sum += __shfl_xor(sum, 1);
  sum += __shfl_xor(sum, 2);
  float inv = 1.f / sum;
  size_t base = (size_t)b * K_ * N_ + n;
#pragma unroll
  for (int kk = 0; kk < 16; kk++)
    aout[base + (size_t)(kk * 4 + kg) * N_] = lg[kk] * inv;
}

// ============ 4) colsum[r] = sum_n attn[r,n],  r = b*K+k ============
__global__ __launch_bounds__(256) void k_colsum2(const float* __restrict__ ant, float* __restrict__ colsum) {
  int r = blockIdx.x, tid = threadIdx.x;
  const float* row = ant + (size_t)r * N_;
  float s = 0;
  for (int n = tid; n < N_; n += 256) s += row[n];
#pragma unroll
  for (int off = 32; off; off >>= 1) s += __shfl_down(s, off);
  __shared__ float red[4];
  if ((tid & 63) == 0) red[tid >> 6] = s;
  __syncthreads();
  if (tid == 0) colsum[r] = red[0] + red[1] + red[2] + red[3];
}

// ============ 5) pi_new + inverse normalizer ============
__global__ void k_pinew(const float* __restrict__ colsum, const float* __restrict__ pi,
                        float* __restrict__ pi_out, float* __restrict__ icn) {
  int b = blockIdx.x, k = threadIdx.x;
  float cs = colsum[b * K_ + k];
  float p = pi[k];
  pi_out[b * K_ + k] = p + GAMMA_F * (cs / (float)N_ - p);
  icn[b * K_ + k] = 1.f / (cs + (float)N_ * 1e-8f);
}

// ==== 6) t_new + cov fused per (b,k): cov via exact identity ====
__global__ __launch_bounds__(256) void k_tnew_cov(const float* __restrict__ ant, const float* __restrict__ icn,
                                                  const float* __restrict__ xf, const float* __restrict__ x2,
                                                  const float* __restrict__ clusters, const float* __restrict__ cov,
                                                  float* __restrict__ tnew_out, float* __restrict__ cov_out) {
  int k = blockIdx.x, b = blockIdx.y;
  int tid = threadIdx.x;
  int c = tid & 63, g = tid >> 6;
  const float* arow = ant + ((size_t)b * K_ + k) * N_;
  const float* x2r = x2 + (size_t)b * N_;
  float acc = 0, ax2 = 0;
#pragma unroll 4
  for (int n = g; n < N_; n += 4) {
    float a = arow[n] + 1e-8f;
    acc += a * xf[((size_t)b * N_ + n) * CD_ + c];
    ax2 += a * x2r[n];
  }
  __shared__ float red[4][64];
  __shared__ float red2[4];
  red[g][c] = acc;
  if (c == 0) red2[g] = ax2;   // ax2 identical across c within a group
  __syncthreads();
  if (tid < 64) {
    float icnv = icn[b * K_ + k];
    float s = (red[0][c] + red[1][c] + red[2][c] + red[3][c]) * icnv;
    float cl = clusters[k * CD_ + c];
    float tv = cl + GAMMA_F * (s - cl);
    tnew_out[((size_t)b * K_ + k) * CD_ + c] = tv;
    float sq = tv * tv;
    float st = s * tv;
#pragma unroll
    for (int off = 32; off; off >>= 1) { sq += __shfl_down(sq, off); st += __shfl_down(st, off); }
    if (c == 0) {
      float ax2t = (red2[0] + red2[1] + red2[2] + red2[3]) * icnv;
      float cv = cov[k];
      float csum = ax2t + sq - 2.f * st;
      cov_out[b * K_ + k] = cv + GAMMA_F * (csum - cv);
    }
  }
}

// ==== 7) centered-A precompute (fuses k_amean): AcH/AcL[r][n] bf16 planes ====
__global__ __launch_bounds__(256) void k_acenter(const float* __restrict__ attn, const float* __restrict__ icn,
                                                 short* __restrict__ AcH, short* __restrict__ AcL) {
  int b = blockIdx.y;
  int n = blockIdx.x * 256 + threadIdx.x;
  const float* base = attn + (size_t)b * K_ * N_ + n;
  const float* ic = icn + b * K_;   // wave-uniform -> scalar loads
  float a[K_];
  float s = 0;
#pragma unroll 8
  for (int k = 0; k < K_; k++) {
    a[k] = base[(size_t)k * N_];
    s += (a[k] + 1e-8f) * ic[k];
  }
  float amean = s * (1.f / (float)K_);
#pragma unroll 8
  for (int k = 0; k < K_; k++) {
    float icv = ic[k];
    float va = fmaf(a[k], icv, 1e-8f * icv) - amean;
    short h, l;
    split_bf(va, h, l);
    AcH[(size_t)(b * K_ + k) * N_ + n] = h;
    AcL[(size_t)(b * K_ + k) * N_ + n] = l;
  }
}

// ==== 8) precompute column-normalized mask as bf16 hi/lo planes ====
__global__ __launch_bounds__(256) void k_mask(short* __restrict__ MH, short* __restrict__ ML) {
  __shared__ float red[4];
  const int m = blockIdx.x;
  const int mi = m / W_, mj = m % W_;
  const int tid = threadIdx.x;
  float e[N_ / 256];
  float s = 0;
#pragma unroll
  for (int it = 0; it < N_ / 256; it++) {
    int n = it * 256 + tid;
    int ni = n / W_, nj = n - (n / W_) * W_;
    int dx = ni - mi, dy = nj - mj;
    e[it] = __expf(-sqrtf((float)(dx * dx + dy * dy)));
    s += e[it];
  }
#pragma unroll
  for (int off = 32; off; off >>= 1) s += __shfl_down(s, off);
  if ((tid & 63) == 0) red[tid >> 6] = s;
  __syncthreads();
  const float imc = 1.f / (red[0] + red[1] + red[2] + red[3]);
#pragma unroll
  for (int it = 0; it < N_ / 256; it++) {
    int n = it * 256 + tid;
    short h, l;
    split_bf(e[it] * imc, h, l);
    MH[(size_t)m * N_ + n] = h;
    ML[(size_t)m * N_ + n] = l;
  }
}

// ================= bf16x3 split-precision MFMA GEMM pair =================
// Direct-from-global fragment loads (operands pre-split in global, laid out
// exactly as MFMA fragments: 16B at [row][k0+quad*8]). No LDS staging, no
// barriers in the K-loop; register prefetch one tile ahead. MFMA sequence and
// values bit-identical to the LDS version.

// ==== 9) gemm1: Ydev[r,m] = sum_n Ac[r,n] * A(n,m) ====
__global__ __launch_bounds__(256) void gemm1_mfma(const short* __restrict__ AcH, const short* __restrict__ AcL,
                                                  const short* __restrict__ MaskH, const short* __restrict__ MaskL,
                                                  short* __restrict__ YdH, short* __restrict__ YdL) {
  const int tid = threadIdx.x;
  const int b = blockIdx.y;
  const int m0 = b * 64, n0 = blockIdx.x * 64;
  const int lane = tid & 63, w = tid >> 6;
  const int fr = lane & 15, quad = lane >> 4;
  const size_t arow = (size_t)(m0 + w * 16 + fr) * N_ + quad * 8;  // A fragment base
  size_t brow[4];
#pragma unroll
  for (int ns = 0; ns < 4; ns++) brow[ns] = (size_t)(n0 + ns * 16 + fr) * N_ + quad * 8;
  f32x4 acc[4] = {};
  // prologue: fragments for tile 0
  bf16x8 ah = *(const bf16x8*)&AcH[arow];
  bf16x8 al = *(const bf16x8*)&AcL[arow];
  bf16x8 bh[4], bl[4];
#pragma unroll
  for (int ns = 0; ns < 4; ns++) {
    bh[ns] = *(const bf16x8*)&MaskH[brow[ns]];
    bl[ns] = *(const bf16x8*)&MaskL[brow[ns]];
  }
  for (int k0 = 0; k0 < N_; k0 += 32) {
    const int kn = (k0 + 32 < N_) ? k0 + 32 : k0;   // last iter: reload (values unused)
    bf16x8 ah1 = *(const bf16x8*)&AcH[arow + kn];
    bf16x8 al1 = *(const bf16x8*)&AcL[arow + kn];
    bf16x8 bh1[4], bl1[4];
#pragma unroll
    for (int ns = 0; ns < 4; ns++) {
      bh1[ns] = *(const bf16x8*)&MaskH[brow[ns] + kn];
      bl1[ns] = *(const bf16x8*)&MaskL[brow[ns] + kn];
    }
#pragma unroll
    for (int ns = 0; ns < 4; ns++) {
      acc[ns] = __builtin_amdgcn_mfma_f32_16x16x32_bf16(ah, bh[ns], acc[ns], 0, 0, 0);
      acc[ns] = __builtin_amdgcn_mfma_f32_16x16x32_bf16(ah, bl[ns], acc[ns], 0, 0, 0);
      acc[ns] = __builtin_amdgcn_mfma_f32_16x16x32_bf16(al, bh[ns], acc[ns], 0, 0, 0);
    }
    ah = ah1; al = al1;
#pragma unroll
    for (int ns = 0; ns < 4; ns++) { bh[ns] = bh1[ns]; bl[ns] = bl1[ns]; }
  }
  // epilogue: split acc -> bf16 hi/lo planes (row w*16+fr, cols ns*16+quad*4..+3)
  const size_t rbase = (size_t)(m0 + w * 16 + fr) * N_ + n0;
#pragma unroll
  for (int ns = 0; ns < 4; ns++) {
    s16x4 h4, l4;
#pragma unroll
    for (int reg = 0; reg < 4; reg++) { short h, l; split_bf(acc[ns][reg], h, l); h4[reg] = h; l4[reg] = l; }
    *(s16x4*)&YdH[rbase + ns * 16 + quad * 4] = h4;
    *(s16x4*)&YdL[rbase + ns * 16 + quad * 4] = l4;
  }
}

// ==== 10) gemm2: D = Ydev @ A == outp_pre - mu_k; outp = D*rstd*sc + bi ====
__global__ __launch_bounds__(256) void gemm2_ln_mfma(const short* __restrict__ YdH, const short* __restrict__ YdL,
                                                     const short* __restrict__ MaskH, const short* __restrict__ MaskL,
                                                     const float* __restrict__ pns, const float* __restrict__ pnb,
                                                     float* __restrict__ outp) {
  __shared__ __align__(16) float S[64][68];
  __shared__ float rstd[64], sc[64], bi[64];
  const int tid = threadIdx.x;
  const int b = blockIdx.y;
  const int m0 = b * 64, n0 = blockIdx.x * 64;
  const int lane = tid & 63, w = tid >> 6;
  const int fr = lane & 15, quad = lane >> 4;
  if (tid < 64) { sc[tid] = pns[tid]; bi[tid] = pnb[tid]; }
  const size_t arow = (size_t)(m0 + w * 16 + fr) * N_ + quad * 8;
  size_t brow[4];
#pragma unroll
  for (int ns = 0; ns < 4; ns++) brow[ns] = (size_t)(n0 + ns * 16 + fr) * N_ + quad * 8;
  f32x4 acc[4] = {};
  bf16x8 yh = *(const bf16x8*)&YdH[arow];
  bf16x8 yl = *(const bf16x8*)&YdL[arow];
  bf16x8 bh[4], bl[4];
#pragma unroll
  for (int ns = 0; ns < 4; ns++) {
    bh[ns] = *(const bf16x8*)&MaskH[brow[ns]];
    bl[ns] = *(const bf16x8*)&MaskL[brow[ns]];
  }
  for (int k0 = 0; k0 < N_; k0 += 32) {
    const int kn = (k0 + 32 < N_) ? k0 + 32 : k0;
    bf16x8 yh1 = *(const bf16x8*)&YdH[arow + kn];
    bf16x8 yl1 = *(const bf16x8*)&YdL[arow + kn];
    bf16x8 bh1[4], bl1[4];
#pragma unroll
    for (int ns = 0; ns < 4; ns++) {
      bh1[ns] = *(const bf16x8*)&MaskH[brow[ns] + kn];
      bl1[ns] = *(const bf16x8*)&MaskL[brow[ns] + kn];
    }
#pragma unroll
    for (int ns = 0; ns < 4; ns++) {
      acc[ns] = __builtin_amdgcn_mfma_f32_16x16x32_bf16(yh, bh[ns], acc[ns], 0, 0, 0);
      acc[ns] = __builtin_amdgcn_mfma_f32_16x16x32_bf16(yh, bl[ns], acc[ns], 0, 0, 0);
      acc[ns] = __builtin_amdgcn_mfma_f32_16x16x32_bf16(yl, bh[ns], acc[ns], 0, 0, 0);
    }
    yh = yh1; yl = yl1;
#pragma unroll
    for (int ns = 0; ns < 4; ns++) { bh[ns] = bh1[ns]; bl[ns] = bl1[ns]; }
  }
  // S[k_row][m_col]; D has zero k-mean -> var = mean_k(D^2)
#pragma unroll
  for (int ns = 0; ns < 4; ns++)
    *(f32x4*)&S[w * 16 + fr][ns * 16 + quad * 4] = acc[ns];
  __syncthreads();
  if (tid < 64) {
    float ss = 0;
#pragma unroll
    for (int k = 0; k < K_; k++) { float d = S[k][tid]; ss += d * d; }
    rstd[tid] = 1.f / sqrtf(ss / (float)K_ + 1e-5f);
  }
  __syncthreads();
  {
    int c = tid & 63, g = tid >> 6;
#pragma unroll
    for (int i = 0; i < 16; i++) {
      int r = g * 16 + i;
      outp[(size_t)(m0 + r) * N_ + n0 + c] = S[r][c] * rstd[c] * sc[r] + bi[r];
    }
  }
}

extern "C" void kernel_launch(void* const* d_in, const int* in_sizes, int n_in,
                              void* d_out, int out_size, void* d_ws, size_t ws_size,
                              hipStream_t stream) {
  const float* x        = (const float*)d_in[0];
  const float* clusters = (const float*)d_in[1];
  const float* pi       = (const float*)d_in[2];
  const float* cov      = (const float*)d_in[3];
  const float* w_proj   = (const float*)d_in[4];
  const float* nt_scale = (const float*)d_in[5];
  const float* nt_bias  = (const float*)d_in[6];
  const float* pn_scale = (const float*)d_in[7];
  const float* pn_bias  = (const float*)d_in[8];
  float* out = (float*)d_out;
  float* w = (float*)d_ws;
  short* YdH = (short*)(w + OFF_XF);                   // overlays xf (dead after k_tnew_cov)
  short* YdL = YdH + (size_t)B_ * K_ * N_;
  short* AcH = (short*)(w + OFF_ANT);                  // centered-A planes
  short* AcL = AcH + (size_t)B_ * K_ * N_;
  short* MaskH = (short*)(w + OFF_MASKH);
  short* MaskL = (short*)(w + OFF_MASKL);
  float* attn = out + OUT_ATTN;                        // [B,K,N], written by k_attn, read downstream

  // input-independent spatial mask first
  k_mask<<<N_, 256, 0, stream>>>(MaskH, MaskL);
  k_proj<<<dim3(N_ / 64, B_), 256, 0, stream>>>(x, w_proj, w + OFF_XF);
  k_templ<<<1, K_, 0, stream>>>(clusters, pi, cov, nt_scale, nt_bias,
                                w + OFF_T, w + OFF_T2, w + OFF_LOGPI, w + OFF_I2C);
  k_attn<<<dim3(N_ / 64, B_), 256, 0, stream>>>(w + OFF_XF, w + OFF_T, w + OFF_T2,
                                                w + OFF_LOGPI, w + OFF_I2C,
                                                attn, w + OFF_X2);
  k_colsum2<<<B_ * K_, 256, 0, stream>>>(attn, w + OFF_CS);
  k_pinew<<<B_, K_, 0, stream>>>(w + OFF_CS, pi, out + OUT_PI, w + OFF_ICN);
  // centered-A precompute (fuses k_amean; amean kept in registers)
  k_acenter<<<dim3(N_ / 256, B_), 256, 0, stream>>>(attn, w + OFF_ICN, AcH, AcL);
  // fused t_new + cov (single pass over xf/attn; cov via exact identity)
  k_tnew_cov<<<dim3(K_, B_), 256, 0, stream>>>(attn, w + OFF_ICN, w + OFF_XF, w + OFF_X2,
                                               clusters, cov, out + OUT_TNEW, out + OUT_COV);
  // Ydev = Ac @ A  -> bf16 hi/lo planes (overlay xf)
  gemm1_mfma<<<dim3(N_ / 64, B_), 256, 0, stream>>>(AcH, AcL, MaskH, MaskL, YdH, YdL);
  // outp = (Ydev @ A) * rstd * sc + bi
  gemm2_ln_mfma<<<dim3(N_ / 64, B_), 256, 0, stream>>>(YdH, YdL, MaskH, MaskL,
                                                       pn_scale, pn_bias, out + OUT_OUTP);
}

// Round 6
// 361.919 us; speedup vs baseline: 1.9820x; 1.9820x over previous
//
#include <hip/hip_runtime.h>
#include <hip/hip_bf16.h>
#include <math.h>

#define B_   16
#define CIN_ 256
#define H_   48
#define W_   48
#define N_   2304
#define K_   64
#define CD_  64

#define GAMMA_F 0.9999999999f
#define KSPLIT 1152   // half of N_

using f32x4  = __attribute__((ext_vector_type(4))) float;
using bf16x8 = __attribute__((ext_vector_type(8))) short;
using s16x4  = __attribute__((ext_vector_type(4))) short;

// fp32 -> (hi, lo) bf16 pair, RNE both times.
__device__ __forceinline__ void split_bf(float x, short& hi, short& lo) {
  unsigned u = __builtin_bit_cast(unsigned, x);
  unsigned r = (u + 0x7FFFu + ((u >> 16) & 1u)) & 0xFFFF0000u;
  hi = (short)(r >> 16);
  float res = x - __builtin_bit_cast(float, r);
  unsigned u2 = __builtin_bit_cast(unsigned, res);
  unsigned r2 = u2 + 0x7FFFu + ((u2 >> 16) & 1u);
  lo = (short)(r2 >> 16);
}

// ---------------- workspace layout (floats) ----------------
constexpr size_t OFF_XF    = 0;                                  // B*N*CD: xf; later split-K partials P0/Q0
constexpr size_t OFF_ANT   = OFF_XF    + (size_t)B_*N_*CD_;      // B*K*N: AcH/AcL planes; later YdH/YdL planes
constexpr size_t OFF_T     = OFF_ANT   + (size_t)B_*K_*N_;       // K*CD
constexpr size_t OFF_T2    = OFF_T     + (size_t)K_*CD_;         // K
constexpr size_t OFF_LOGPI = OFF_T2    + K_;                     // K
constexpr size_t OFF_I2C   = OFF_LOGPI + K_;                     // K
constexpr size_t OFF_X2    = OFF_I2C   + K_;                     // B*N (x2)
constexpr size_t OFF_CS    = OFF_X2    + (size_t)B_*N_;          // B*K
constexpr size_t OFF_ICN   = OFF_CS    + (size_t)B_*K_;          // B*K
// precomputed column-normalized spatial mask, bf16 hi/lo planes, [mcol][token]
constexpr size_t OFF_MASKH = OFF_ICN   + (size_t)B_*K_;          // N*N shorts = N*N/2 floats
constexpr size_t OFF_MASKL = OFF_MASKH + (size_t)N_*N_/2;        // N*N shorts

// ---------------- output layout (fp32 elements) ----------------
constexpr size_t OUT_OUTP = 0;
constexpr size_t OUT_ATTN = (size_t)B_*K_*N_;
constexpr size_t OUT_TNEW = OUT_ATTN + (size_t)B_*K_*N_;
constexpr size_t OUT_PI   = OUT_TNEW + (size_t)B_*K_*CD_;
constexpr size_t OUT_COV  = OUT_PI   + (size_t)B_*K_;

// ============ 1) projection: xf[b,n,c] = sum_i x[b,i,n]*w[c,i] ============
__global__ __launch_bounds__(256) void k_proj(const float* __restrict__ x, const float* __restrict__ wp,
                                              float* __restrict__ xf) {
  __shared__ float xs[32][64];
  __shared__ float ws_[32][65];
  int b = blockIdx.y, n0 = blockIdx.x * 64;
  int tid = threadIdx.x;
  int nn = tid & 63, cg = tid >> 6;
  float acc[16];
#pragma unroll
  for (int j = 0; j < 16; j++) acc[j] = 0.f;
  for (int i0 = 0; i0 < CIN_; i0 += 32) {
#pragma unroll
    for (int j = 0; j < 8; j++) {
      int ii = cg * 8 + j;
      xs[ii][nn] = x[((size_t)b * CIN_ + i0 + ii) * N_ + n0 + nn];
    }
    {
      int c = tid >> 2, iq = (tid & 3) * 8;
#pragma unroll
      for (int j = 0; j < 8; j++)
        ws_[iq + j][c] = wp[(size_t)c * CIN_ + i0 + iq + j];
    }
    __syncthreads();
#pragma unroll
    for (int ii = 0; ii < 32; ++ii) {
      float xv = xs[ii][nn];
#pragma unroll
      for (int j = 0; j < 16; j++) acc[j] += xv * ws_[ii][cg * 16 + j];
    }
    __syncthreads();
  }
  float* dst = xf + ((size_t)b * N_ + n0 + nn) * CD_ + cg * 16;
#pragma unroll
  for (int j4 = 0; j4 < 4; j4++)
    *(float4*)(dst + j4 * 4) = make_float4(acc[j4*4], acc[j4*4+1], acc[j4*4+2], acc[j4*4+3]);
}

// ============ 2) templates LN + per-k constants ============
__global__ void k_templ(const float* __restrict__ clusters, const float* __restrict__ pi,
                        const float* __restrict__ cov, const float* __restrict__ nsc,
                        const float* __restrict__ nbi, float* __restrict__ t, float* __restrict__ t2,
                        float* __restrict__ logpi, float* __restrict__ i2c) {
  int k = threadIdx.x;  // 64 threads
  float v[CD_];
  float m = 0;
#pragma unroll
  for (int c = 0; c < CD_; c++) { v[c] = clusters[k * CD_ + c]; m += v[c]; }
  m /= CD_;
  float var = 0;
#pragma unroll
  for (int c = 0; c < CD_; c++) { float d = v[c] - m; var += d * d; }
  var /= CD_;
  float inv = 1.f / sqrtf(var + 1e-5f);
  float s2 = 0;
#pragma unroll
  for (int c = 0; c < CD_; c++) {
    float tv = (v[c] - m) * inv * nsc[c] + nbi[c];
    t[k * CD_ + c] = tv;
    s2 += tv * tv;
  }
  t2[k] = s2;
  float p = pi[k], cv = cov[k];
  logpi[k] = logf(p) - 0.5f * logf(cv);
  i2c[k] = 0.5f / cv;
}

// ==== 3) distances + softmax (split-K: 4 threads/token, 16 k each) ====
__global__ __launch_bounds__(256) void k_attn(const float* __restrict__ xf, const float* __restrict__ t,
                                              const float* __restrict__ t2, const float* __restrict__ logpi,
                                              const float* __restrict__ i2c,
                                              float* __restrict__ aout, float* __restrict__ x2o) {
  __shared__ __align__(16) float ts[K_][72];
  __shared__ float t2s[K_], lps[K_], ics[K_];
  int tid = threadIdx.x;
  for (int i = tid; i < K_ * CD_; i += 256) ts[i >> 6][i & 63] = t[i];
  if (tid < K_) { t2s[tid] = t2[tid]; lps[tid] = logpi[tid]; ics[tid] = i2c[tid]; }
  __syncthreads();
  int b = blockIdx.y;
  int tok = tid >> 2, kg = tid & 3;            // 4 threads per token
  int n = blockIdx.x * 64 + tok;
  const float4* xr = (const float4*)(xf + ((size_t)b * N_ + n) * CD_);
  float4 xv[16];
#pragma unroll
  for (int i = 0; i < 16; i++) xv[i] = xr[i];
  float x2 = 0;
#pragma unroll
  for (int i = 0; i < 16; i++) x2 += xv[i].x * xv[i].x + xv[i].y * xv[i].y + xv[i].z * xv[i].z + xv[i].w * xv[i].w;
  if (kg == 0) x2o[(size_t)b * N_ + n] = x2;
  float lg[16];
#pragma unroll
  for (int kk = 0; kk < 16; kk++) {
    int k = kk * 4 + kg;
    const float4* tk = (const float4*)&ts[k][0];
    // 4 independent partial chains (fp32 reassociation only)
    float d0 = 0, d1 = 0, d2 = 0, d3 = 0;
#pragma unroll
    for (int i = 0; i < 16; i += 4) {
      float4 t0 = tk[i], t1 = tk[i + 1], t2v = tk[i + 2], t3 = tk[i + 3];
      d0 += xv[i].x * t0.x + xv[i].y * t0.y + xv[i].z * t0.z + xv[i].w * t0.w;
      d1 += xv[i+1].x * t1.x + xv[i+1].y * t1.y + xv[i+1].z * t1.z + xv[i+1].w * t1.w;
      d2 += xv[i+2].x * t2v.x + xv[i+2].y * t2v.y + xv[i+2].z * t2v.z + xv[i+2].w * t2v.w;
      d3 += xv[i+3].x * t3.x + xv[i+3].y * t3.y + xv[i+3].z * t3.z + xv[i+3].w * t3.w;
    }
    float dot = (d0 + d1) + (d2 + d3);
    lg[kk] = lps[k] - (x2 + t2s[k] - 2.f * dot) * ics[k];
  }
  float mx = lg[0];
#pragma unroll
  for (int kk = 1; kk < 16; kk++) mx = fmaxf(mx, lg[kk]);
  mx = fmaxf(mx, __shfl_xor(mx, 1));
  mx = fmaxf(mx, __shfl_xor(mx, 2));
  float sum = 0;
#pragma unroll
  for (int kk = 0; kk < 16; kk++) { lg[kk] = __expf(lg[kk] - mx); sum += lg[kk]; }
  sum += __shfl_xor(sum, 1);
  sum += __shfl_xor(sum, 2);
  float inv = 1.f / sum;
  size_t base = (size_t)b * K_ * N_ + n;
#pragma unroll
  for (int kk = 0; kk < 16; kk++)
    aout[base + (size_t)(kk * 4 + kg) * N_] = lg[kk] * inv;
}

// ============ 4) colsum[r] = sum_n attn[r,n],  r = b*K+k ============
__global__ __launch_bounds__(256) void k_colsum2(const float* __restrict__ ant, float* __restrict__ colsum) {
  int r = blockIdx.x, tid = threadIdx.x;
  const float* row = ant + (size_t)r * N_;
  float s = 0;
  for (int n = tid; n < N_; n += 256) s += row[n];
#pragma unroll
  for (int off = 32; off; off >>= 1) s += __shfl_down(s, off);
  __shared__ float red[4];
  if ((tid & 63) == 0) red[tid >> 6] = s;
  __syncthreads();
  if (tid == 0) colsum[r] = red[0] + red[1] + red[2] + red[3];
}

// ============ 5) pi_new + inverse normalizer ============
__global__ void k_pinew(const float* __restrict__ colsum, const float* __restrict__ pi,
                        float* __restrict__ pi_out, float* __restrict__ icn) {
  int b = blockIdx.x, k = threadIdx.x;
  float cs = colsum[b * K_ + k];
  float p = pi[k];
  pi_out[b * K_ + k] = p + GAMMA_F * (cs / (float)N_ - p);
  icn[b * K_ + k] = 1.f / (cs + (float)N_ * 1e-8f);
}

// ==== 6) t_new + cov fused per (b,k): cov via exact identity ====
__global__ __launch_bounds__(256) void k_tnew_cov(const float* __restrict__ ant, const float* __restrict__ icn,
                                                  const float* __restrict__ xf, const float* __restrict__ x2,
                                                  const float* __restrict__ clusters, const float* __restrict__ cov,
                                                  float* __restrict__ tnew_out, float* __restrict__ cov_out) {
  int k = blockIdx.x, b = blockIdx.y;
  int tid = threadIdx.x;
  int c = tid & 63, g = tid >> 6;
  const float* arow = ant + ((size_t)b * K_ + k) * N_;
  const float* x2r = x2 + (size_t)b * N_;
  float acc = 0, ax2 = 0;
#pragma unroll 4
  for (int n = g; n < N_; n += 4) {
    float a = arow[n] + 1e-8f;
    acc += a * xf[((size_t)b * N_ + n) * CD_ + c];
    ax2 += a * x2r[n];
  }
  __shared__ float red[4][64];
  __shared__ float red2[4];
  red[g][c] = acc;
  if (c == 0) red2[g] = ax2;   // ax2 identical across c within a group
  __syncthreads();
  if (tid < 64) {
    float icnv = icn[b * K_ + k];
    float s = (red[0][c] + red[1][c] + red[2][c] + red[3][c]) * icnv;
    float cl = clusters[k * CD_ + c];
    float tv = cl + GAMMA_F * (s - cl);
    tnew_out[((size_t)b * K_ + k) * CD_ + c] = tv;
    float sq = tv * tv;
    float st = s * tv;
#pragma unroll
    for (int off = 32; off; off >>= 1) { sq += __shfl_down(sq, off); st += __shfl_down(st, off); }
    if (c == 0) {
      float ax2t = (red2[0] + red2[1] + red2[2] + red2[3]) * icnv;
      float cv = cov[k];
      float csum = ax2t + sq - 2.f * st;
      cov_out[b * K_ + k] = cv + GAMMA_F * (csum - cv);
    }
  }
}

// ==== 7) centered-A precompute (fuses k_amean): AcH/AcL[r][n] bf16 planes ====
__global__ __launch_bounds__(256) void k_acenter(const float* __restrict__ attn, const float* __restrict__ icn,
                                                 short* __restrict__ AcH, short* __restrict__ AcL) {
  int b = blockIdx.y;
  int n = blockIdx.x * 256 + threadIdx.x;
  const float* base = attn + (size_t)b * K_ * N_ + n;
  const float* ic = icn + b * K_;   // wave-uniform -> scalar loads
  float a[K_];
  float s = 0;
#pragma unroll 8
  for (int k = 0; k < K_; k++) {
    a[k] = base[(size_t)k * N_];
    s += (a[k] + 1e-8f) * ic[k];
  }
  float amean = s * (1.f / (float)K_);
#pragma unroll 8
  for (int k = 0; k < K_; k++) {
    float icv = ic[k];
    float va = fmaf(a[k], icv, 1e-8f * icv) - amean;
    short h, l;
    split_bf(va, h, l);
    AcH[(size_t)(b * K_ + k) * N_ + n] = h;
    AcL[(size_t)(b * K_ + k) * N_ + n] = l;
  }
}

// ==== 8) precompute column-normalized mask as bf16 hi/lo planes ====
__global__ __launch_bounds__(256) void k_mask(short* __restrict__ MH, short* __restrict__ ML) {
  __shared__ float red[4];
  const int m = blockIdx.x;
  const int mi = m / W_, mj = m % W_;
  const int tid = threadIdx.x;
  float e[N_ / 256];
  float s = 0;
#pragma unroll
  for (int it = 0; it < N_ / 256; it++) {
    int n = it * 256 + tid;
    int ni = n / W_, nj = n - (n / W_) * W_;
    int dx = ni - mi, dy = nj - mj;
    e[it] = __expf(-sqrtf((float)(dx * dx + dy * dy)));
    s += e[it];
  }
#pragma unroll
  for (int off = 32; off; off >>= 1) s += __shfl_down(s, off);
  if ((tid & 63) == 0) red[tid >> 6] = s;
  __syncthreads();
  const float imc = 1.f / (red[0] + red[1] + red[2] + red[3]);
#pragma unroll
  for (int it = 0; it < N_ / 256; it++) {
    int n = it * 256 + tid;
    short h, l;
    split_bf(e[it] * imc, h, l);
    MH[(size_t)m * N_ + n] = h;
    ML[(size_t)m * N_ + n] = l;
  }
}

// ================= bf16x3 split-precision MFMA GEMM pair =================
// LDS double-buffered, ONE barrier per K-step, register prefetch one tile
// ahead (round-4 structure, proven). NEW: 2x2 wave-subtiles (each wave owns a
// 32x32 quadrant -> B-fragment LDS reads halved) and split-K x2 (blockIdx.z
// picks K half; partial fp32 sums combined in a separate kernel). Per-output
// accumulation order within a half is bit-identical; only p0+p1 reassociates.

template<int GEMM>
__global__ __launch_bounds__(256) void gemm_splitk(const short* __restrict__ AH, const short* __restrict__ AL,
                                                   const short* __restrict__ MaskH, const short* __restrict__ MaskL,
                                                   float* __restrict__ P0, float* __restrict__ P1) {
  __shared__ __align__(16) short Ah[2][64][40];
  __shared__ __align__(16) short Al[2][64][40];
  __shared__ __align__(16) short Bh[2][64][40];
  __shared__ __align__(16) short Bl[2][64][40];
  const int tid = threadIdx.x;
  const int b = blockIdx.y;
  const int z = blockIdx.z;
  const int m0 = b * 64, n0 = blockIdx.x * 64;
  const int lane = tid & 63, w = tid >> 6;
  const int fr = lane & 15, quad = lane >> 4;
  const int wr = (w >> 1) * 32;        // wave row origin in tile
  const int wc = (w & 1) * 32;         // wave col origin in tile
  const int srow = tid >> 2;           // staging row 0..63
  const int skq  = (tid & 3) * 8;      // staging k-offset {0,8,16,24}
  const int zb = z * KSPLIT;
  const size_t mrow = (size_t)(n0 + srow) * N_;
  const size_t abase = (size_t)(m0 + srow) * N_ + skq;
  f32x4 acc[2][2] = {};
  // prologue: loads for tile 0 of this K-half
  bf16x8 ah = *(const bf16x8*)&AH[abase + zb];
  bf16x8 al = *(const bf16x8*)&AL[abase + zb];
  bf16x8 mh = *(const bf16x8*)&MaskH[mrow + zb + skq];
  bf16x8 ml = *(const bf16x8*)&MaskL[mrow + zb + skq];
  for (int it = 0; it < KSPLIT / 32; ++it) {
    const int c = it & 1;
    *(bf16x8*)&Ah[c][srow][skq] = ah;
    *(bf16x8*)&Al[c][srow][skq] = al;
    *(bf16x8*)&Bh[c][srow][skq] = mh;
    *(bf16x8*)&Bl[c][srow][skq] = ml;
    if (it + 1 < KSPLIT / 32) {   // prefetch next tile (lands during MFMA phase)
      const int kn = zb + (it + 1) * 32;
      ah = *(const bf16x8*)&AH[abase + kn];
      al = *(const bf16x8*)&AL[abase + kn];
      mh = *(const bf16x8*)&MaskH[mrow + kn + skq];
      ml = *(const bf16x8*)&MaskL[mrow + kn + skq];
    }
    __syncthreads();
    bf16x8 afh[2], afl[2], bfh[2], bfl[2];
#pragma unroll
    for (int i = 0; i < 2; i++) {
      afh[i] = *(const bf16x8*)&Ah[c][wr + i * 16 + fr][quad * 8];
      afl[i] = *(const bf16x8*)&Al[c][wr + i * 16 + fr][quad * 8];
      bfh[i] = *(const bf16x8*)&Bh[c][wc + i * 16 + fr][quad * 8];
      bfl[i] = *(const bf16x8*)&Bl[c][wc + i * 16 + fr][quad * 8];
    }
#pragma unroll
    for (int i = 0; i < 2; i++)
#pragma unroll
      for (int j = 0; j < 2; j++) {
        acc[i][j] = __builtin_amdgcn_mfma_f32_16x16x32_bf16(afh[i], bfh[j], acc[i][j], 0, 0, 0);
        acc[i][j] = __builtin_amdgcn_mfma_f32_16x16x32_bf16(afh[i], bfl[j], acc[i][j], 0, 0, 0);
        acc[i][j] = __builtin_amdgcn_mfma_f32_16x16x32_bf16(afl[i], bfh[j], acc[i][j], 0, 0, 0);
      }
    // no trailing barrier: next iter writes the other buffer
  }
  // store fp32 partials: row = m0+wr+i*16+fr, col = n0+wc+j*16+quad*4..+3
  float* P = z ? P1 : P0;
#pragma unroll
  for (int i = 0; i < 2; i++)
#pragma unroll
    for (int j = 0; j < 2; j++)
      *(f32x4*)&P[(size_t)(m0 + wr + i * 16 + fr) * N_ + n0 + wc + j * 16 + quad * 4] = acc[i][j];
}

// ==== combine1: Yd = split_bf(P0 + P1) -> bf16 hi/lo planes ====
__global__ __launch_bounds__(256) void k_combine1(const float* __restrict__ P0, const float* __restrict__ P1,
                                                  short* __restrict__ YdH, short* __restrict__ YdL) {
  const int b = blockIdx.y, n0 = blockIdx.x * 64;
  const int tid = threadIdx.x;
  const int row = tid >> 2, coff = (tid & 3) * 16;
  const size_t base = (size_t)(b * 64 + row) * N_ + n0 + coff;
#pragma unroll
  for (int q = 0; q < 4; q++) {
    float4 a = *(const float4*)&P0[base + q * 4];
    float4 d = *(const float4*)&P1[base + q * 4];
    s16x4 h4, l4;
    short h, l;
    split_bf(a.x + d.x, h, l); h4[0] = h; l4[0] = l;
    split_bf(a.y + d.y, h, l); h4[1] = h; l4[1] = l;
    split_bf(a.z + d.z, h, l); h4[2] = h; l4[2] = l;
    split_bf(a.w + d.w, h, l); h4[3] = h; l4[3] = l;
    *(s16x4*)&YdH[base + q * 4] = h4;
    *(s16x4*)&YdL[base + q * 4] = l4;
  }
}

// ==== combine2: D = Q0 + Q1; LN over k (zero-mean by construction) -> outp ====
__global__ __launch_bounds__(256) void k_combine2_ln(const float* __restrict__ Q0, const float* __restrict__ Q1,
                                                     const float* __restrict__ pns, const float* __restrict__ pnb,
                                                     float* __restrict__ outp) {
  __shared__ __align__(16) float S[64][68];
  __shared__ float rstd[64], sc[64], bi[64];
  const int b = blockIdx.y, n0 = blockIdx.x * 64;
  const int tid = threadIdx.x;
  const int m0 = b * 64;
  if (tid < 64) { sc[tid] = pns[tid]; bi[tid] = pnb[tid]; }
  const int row = tid >> 2, coff = (tid & 3) * 16;
  const size_t base = (size_t)(m0 + row) * N_ + n0 + coff;
#pragma unroll
  for (int q = 0; q < 4; q++) {
    float4 a = *(const float4*)&Q0[base + q * 4];
    float4 d = *(const float4*)&Q1[base + q * 4];
    *(f32x4*)&S[row][coff + q * 4] = f32x4{a.x + d.x, a.y + d.y, a.z + d.z, a.w + d.w};
  }
  __syncthreads();   // all reads of Q1 (overlays outp region) complete before writes
  if (tid < 64) {
    float ss = 0;
#pragma unroll
    for (int k = 0; k < K_; k++) { float d = S[k][tid]; ss += d * d; }
    rstd[tid] = 1.f / sqrtf(ss / (float)K_ + 1e-5f);
  }
  __syncthreads();
  {
    int c = tid & 63, g = tid >> 6;
#pragma unroll
    for (int i = 0; i < 16; i++) {
      int r = g * 16 + i;
      outp[(size_t)(m0 + r) * N_ + n0 + c] = S[r][c] * rstd[c] * sc[r] + bi[r];
    }
  }
}

extern "C" void kernel_launch(void* const* d_in, const int* in_sizes, int n_in,
                              void* d_out, int out_size, void* d_ws, size_t ws_size,
                              hipStream_t stream) {
  const float* x        = (const float*)d_in[0];
  const float* clusters = (const float*)d_in[1];
  const float* pi       = (const float*)d_in[2];
  const float* cov      = (const float*)d_in[3];
  const float* w_proj   = (const float*)d_in[4];
  const float* nt_scale = (const float*)d_in[5];
  const float* nt_bias  = (const float*)d_in[6];
  const float* pn_scale = (const float*)d_in[7];
  const float* pn_bias  = (const float*)d_in[8];
  float* out = (float*)d_out;
  float* w = (float*)d_ws;
  short* AcH = (short*)(w + OFF_ANT);                  // centered-A planes (live until gemm1 done)
  short* AcL = AcH + (size_t)B_ * K_ * N_;
  short* YdH = AcH;                                    // combine1 overwrites dead Ac region
  short* YdL = AcL;
  short* MaskH = (short*)(w + OFF_MASKH);
  short* MaskL = (short*)(w + OFF_MASKL);
  float* attn = out + OUT_ATTN;                        // [B,K,N], written by k_attn, read downstream
  float* Phalf0 = w + OFF_XF;                          // split-K partials: XF region (xf dead after k_tnew_cov)
  float* Phalf1 = out + OUT_OUTP;                      // split-K partials: outp region (written last by combine2)

  // input-independent spatial mask first
  k_mask<<<N_, 256, 0, stream>>>(MaskH, MaskL);
  k_proj<<<dim3(N_ / 64, B_), 256, 0, stream>>>(x, w_proj, w + OFF_XF);
  k_templ<<<1, K_, 0, stream>>>(clusters, pi, cov, nt_scale, nt_bias,
                                w + OFF_T, w + OFF_T2, w + OFF_LOGPI, w + OFF_I2C);
  k_attn<<<dim3(N_ / 64, B_), 256, 0, stream>>>(w + OFF_XF, w + OFF_T, w + OFF_T2,
                                                w + OFF_LOGPI, w + OFF_I2C,
                                                attn, w + OFF_X2);
  k_colsum2<<<B_ * K_, 256, 0, stream>>>(attn, w + OFF_CS);
  k_pinew<<<B_, K_, 0, stream>>>(w + OFF_CS, pi, out + OUT_PI, w + OFF_ICN);
  // centered-A precompute (fuses k_amean; amean kept in registers)
  k_acenter<<<dim3(N_ / 256, B_), 256, 0, stream>>>(attn, w + OFF_ICN, AcH, AcL);
  // fused t_new + cov (single pass over xf/attn; xf dead afterwards)
  k_tnew_cov<<<dim3(K_, B_), 256, 0, stream>>>(attn, w + OFF_ICN, w + OFF_XF, w + OFF_X2,
                                               clusters, cov, out + OUT_TNEW, out + OUT_COV);
  // gemm1 split-K: partials -> XF / OUTP regions
  gemm_splitk<1><<<dim3(N_ / 64, B_, 2), 256, 0, stream>>>(AcH, AcL, MaskH, MaskL, Phalf0, Phalf1);
  // Yd = split_bf(p0+p1) -> bf16 planes overwriting dead Ac region
  k_combine1<<<dim3(N_ / 64, B_), 256, 0, stream>>>(Phalf0, Phalf1, YdH, YdL);
  // gemm2 split-K: partials -> XF / OUTP regions (Yd read from Ac region)
  gemm_splitk<2><<<dim3(N_ / 64, B_, 2), 256, 0, stream>>>(YdH, YdL, MaskH, MaskL, Phalf0, Phalf1);
  // outp = LN(q0+q1) (in-block read-before-write on the outp region)
  k_combine2_ln<<<dim3(N_ / 64, B_), 256, 0, stream>>>(Phalf0, Phalf1, pn_scale, pn_bias, out + OUT_OUTP);
}